// Round 2
// baseline (9142.661 us; speedup 1.0000x reference)
//
#include <hip/hip_runtime.h>
#include <math.h>

#define BATCH 128
#define TSTEPS 4096
#define INDIM 13

// Shared memory layout (one 224-float block, zero-initialized each launch):
//  zL[0:80]  = smem+0    [x(13) | o0(35) | o1(23) | o2(6) | pad(3)]  LSTM input
//  z0[0:48]  = smem+80   [x(13) | h0_lstm(35)]                       CfC0 input
//  z1[0:60]  = smem+128  [o0(35) | h1_lstm(23) | pad(2)]             CfC1 input
//  z2[0:32]  = smem+188  [o1(23) | h2_lstm(6) | pad(3)]              CfC2 input
// Pads are multiplied by zero weight-register pads, but zero-init anyway so
// every launch is bit-identical regardless of leftover LDS state.

__device__ __forceinline__ float fsig(float x) {
    return 1.f / (1.f + __expf(-x));   // exact division (compiler-refined)
}
__device__ __forceinline__ float ftanh(float x) {
    float s = fsig(x + x);
    return s + s - 1.f;
}
__device__ __forceinline__ float fsoftplus(float x) {
    return (x > 15.f) ? x : __logf(1.f + __expf(x));
}

// res = dot(z[0:4*N4], w[0:4*N4]); z in LDS (wave-broadcast reads), w in regs
#define DOT4(res, zarr, warr, N4) do {                      \
    float _a0=0.f,_a1=0.f,_a2=0.f,_a3=0.f;                  \
    _Pragma("unroll")                                       \
    for (int _k=0;_k<(N4);++_k){                            \
      float4 _zv = *(const float4*)&zarr[4*_k];             \
      _a0 += _zv.x*warr[4*_k+0];                            \
      _a1 += _zv.y*warr[4*_k+1];                            \
      _a2 += _zv.z*warr[4*_k+2];                            \
      _a3 += _zv.w*warr[4*_k+3];                            \
    }                                                       \
    res = (_a0+_a1)+(_a2+_a3);                              \
  } while(0)

// Gather the 4 values of this lane-quad. Lane with (t&3)==sel owns value sel.
// After: v0..v3 = quad values 0..3 on every lane of the quad.
__device__ __forceinline__ void quad_gather(float own, int sel,
                                            float& v0, float& v1,
                                            float& v2, float& v3) {
    float b = __shfl_xor(own, 1, 64);   // value (sel^1)
    float c = __shfl_xor(own, 2, 64);   // value (sel^2)
    float d = __shfl_xor(b,   2, 64);   // value (sel^3)
    v0 = (sel==0)?own:(sel==1)?b  :(sel==2)?c  :d;
    v1 = (sel==0)?b  :(sel==1)?own:(sel==2)?d  :c;
    v2 = (sel==0)?c  :(sel==1)?d  :(sel==2)?own:b;
    v3 = (sel==0)?d  :(sel==1)?c  :(sel==2)?b  :own;
}

__global__ __launch_bounds__(256, 1)
void rnn_kernel(const float* __restrict__ x,
                const float* __restrict__ lstm_wi, const float* __restrict__ lstm_wh,
                const float* __restrict__ lstm_b,
                const float* __restrict__ c0w1, const float* __restrict__ c0w2,
                const float* __restrict__ c0wa, const float* __restrict__ c0wb,
                const float* __restrict__ c0b1, const float* __restrict__ c0b2,
                const float* __restrict__ c0ba, const float* __restrict__ c0bb,
                const float* __restrict__ c1w1, const float* __restrict__ c1w2,
                const float* __restrict__ c1wa, const float* __restrict__ c1wb,
                const float* __restrict__ c1b1, const float* __restrict__ c1b2,
                const float* __restrict__ c1ba, const float* __restrict__ c1bb,
                const float* __restrict__ c2w1, const float* __restrict__ c2w2,
                const float* __restrict__ c2wa, const float* __restrict__ c2wb,
                const float* __restrict__ c2b1, const float* __restrict__ c2b2,
                const float* __restrict__ c2ba, const float* __restrict__ c2bb,
                float* __restrict__ out)
{
    const int bb = blockIdx.x;
    const int t  = threadIdx.x;
    const int g  = t & 3;      // quad slot: gate / branch type
    const int u  = t >> 2;     // quad index: unit / output row

    __shared__ __align__(16) float smem[224];
    float* zL = smem;
    float* z0 = smem + 80;
    float* z1 = smem + 128;
    float* z2 = smem + 188;

    const long xbase = (long)bb * TSTEPS * INDIM;
    const long obase = (long)bb * TSTEPS * 6;

    // ---- weights into registers ----
    // LSTM: thread (u,g) owns gate-row r = g*64+u  ([ia;ig;fg;og] blocks)
    float wLr[80]; float bLr;
    {
        const int r = g * 64 + u;
        const float* wi = lstm_wi + r * 13;
        const float* wh = lstm_wh + r * 64;
        #pragma unroll
        for (int k = 0; k < 13; ++k) wLr[k] = wi[k];
        #pragma unroll
        for (int k = 0; k < 64; ++k) wLr[13 + k] = wh[k];
        wLr[77] = 0.f; wLr[78] = 0.f; wLr[79] = 0.f;
        bLr = lstm_b[r];
    }
    // CfC0: quads 0..34 (t<140), row j=u, branch g in {w1,w2,wa,wb}
    const bool act0 = (t < 140);
    float w0r[48]; float b0r = 0.f;
    if (act0) {
        const float* W = (g==0 ? c0w1 : g==1 ? c0w2 : g==2 ? c0wa : c0wb) + u * 48;
        #pragma unroll
        for (int k = 0; k < 48; ++k) w0r[k] = W[k];
        b0r = (g==0 ? c0b1 : g==1 ? c0b2 : g==2 ? c0ba : c0bb)[u];
    }
    // CfC1: quads 35..57 (t in [140,232)), row j1=u-35
    const bool act1 = (u >= 35 && u < 58);
    const int  j1   = u - 35;
    float w1r[60]; float b1r = 0.f;
    if (act1) {
        const float* W = (g==0 ? c1w1 : g==1 ? c1w2 : g==2 ? c1wa : c1wb) + j1 * 58;
        #pragma unroll
        for (int k = 0; k < 58; ++k) w1r[k] = W[k];
        w1r[58] = 0.f; w1r[59] = 0.f;
        b1r = (g==0 ? c1b1 : g==1 ? c1b2 : g==2 ? c1ba : c1bb)[j1];
    }
    // CfC2: quads 58..63 (t in [232,256)), row j2=u-58
    const bool act2 = (u >= 58);
    const int  j2   = u - 58;
    float w2r[32]; float b2r = 0.f;
    if (act2) {
        const float* W = (g==0 ? c2w1 : g==1 ? c2w2 : g==2 ? c2wa : c2wb) + j2 * 29;
        #pragma unroll
        for (int k = 0; k < 29; ++k) w2r[k] = W[k];
        w2r[29] = 0.f; w2r[30] = 0.f; w2r[31] = 0.f;
        b2r = (g==0 ? c2b1 : g==1 ? c2b2 : g==2 ? c2ba : c2bb)[j2];
    }

    const bool pfl = (t >= 96 && t < 109);  // x-prefetch lanes (not in act2)
    float creg = 0.f;                        // cell state, replicated per quad

    // ---- init LDS: zero everything, then x_0 ----
    if (t >= 13 && t < 224) smem[t] = 0.f;
    if (t < 13)             zL[t] = x[xbase + t];
    __syncthreads();

    #pragma unroll 1
    for (int ts = 0; ts < TSTEPS; ++ts) {
        // ---- phase 1: LSTM (all 256 threads) ----
        float xn = 0.f;
        if (pfl && (ts + 1) < TSTEPS)
            xn = x[xbase + (long)(ts + 1) * 13 + (t - 96)];
        if (g == 1 && u < 13) z0[u] = zL[u];   // copy x_t into CfC0 input

        float dL; DOT4(dL, zL, wLr, 20); dL += bLr;
        float iav, igv, fgv, ogv;
        quad_gather(dL, g, iav, igv, fgv, ogv);
        float cn = creg * fsig(fgv + 1.f) + ftanh(iav) * fsig(igv);
        creg = cn;                              // identical on all 4 quad lanes
        float hl = ftanh(cn) * fsig(ogv);
        if (g == 0) {
            if (u < 35)      z0[13 + u] = hl;   // h0
            else if (u < 58) z1[u]      = hl;   // h1 at z1[35..57]
            else             z2[u - 35] = hl;   // h2 at z2[23..28]
        }
        __syncthreads();

        // ---- phase 2: CfC layer 0 ----
        if (act0) {
            float dd; DOT4(dd, z0, w0r, 12); dd += b0r;
            float f1d, f2d, tad, tbd;
            quad_gather(dd, g, f1d, f2d, tad, tbd);
            if (g == 0) {
                float tg = fsig(tad + tbd);
                float f1 = ftanh(f1d), f2 = ftanh(f2d);
                float o = f1 + tg * (f2 - f1);
                z1[u] = o;          // input to CfC1
                zL[13 + u] = o;     // new h[0:35]
            }
        }
        __syncthreads();

        // ---- phase 3: CfC layer 1 ----
        if (act1) {
            float dd; DOT4(dd, z1, w1r, 15); dd += b1r;
            float f1d, f2d, tad, tbd;
            quad_gather(dd, g, f1d, f2d, tad, tbd);
            if (g == 0) {
                float tg = fsig(tad + tbd);
                float f1 = ftanh(f1d), f2 = ftanh(f2d);
                float o = f1 + tg * (f2 - f1);
                z2[j1] = o;         // input to CfC2
                zL[48 + j1] = o;    // new h[35:58]
            }
        }
        __syncthreads();

        // ---- phase 4: CfC layer 2 + x_{t+1} commit ----
        if (act2) {
            float dd; DOT4(dd, z2, w2r, 8); dd += b2r;
            float f1d, f2d, tad, tbd;
            quad_gather(dd, g, f1d, f2d, tad, tbd);
            if (g == 0) {
                float tg = fsig(tad + tbd);
                float f1 = ftanh(f1d), f2 = ftanh(f2d);
                float o = f1 + tg * (f2 - f1);
                out[obase + (long)ts * 6 + j2] = o;  // raw cfc_out
                zL[71 + j2] = o;                     // new h[58:64]
            }
        } else if (pfl) {
            zL[t - 96] = xn;                         // commit x_{t+1}
        }
        __syncthreads();
    }
}

// ---- head: rewrite pred in place, write unc ----
#define S_GW1 0
#define S_GB1 192
#define S_GW2 224
#define S_GB2 320
#define S_AW1 323
#define S_AB1 515
#define S_AW2 547
#define S_AB2 643
#define S_UW1 646
#define S_UB1 742
#define S_UW2 758
#define S_UB2 854
#define S_TOT 860

__global__ __launch_bounds__(256)
void head_kernel(const float* __restrict__ gw1, const float* __restrict__ gb1,
                 const float* __restrict__ gw2, const float* __restrict__ gb2,
                 const float* __restrict__ aw1, const float* __restrict__ ab1,
                 const float* __restrict__ aw2, const float* __restrict__ ab2,
                 const float* __restrict__ uw1, const float* __restrict__ ub1,
                 const float* __restrict__ uw2, const float* __restrict__ ub2,
                 float* __restrict__ out)
{
    __shared__ float s[S_TOT];
    const int t = threadIdx.x;
    if (t < 192) { s[S_GW1 + t] = gw1[t]; s[S_AW1 + t] = aw1[t]; }
    if (t < 96)  { s[S_GW2 + t] = gw2[t]; s[S_AW2 + t] = aw2[t];
                   s[S_UW1 + t] = uw1[t]; s[S_UW2 + t] = uw2[t]; }
    if (t < 32)  { s[S_GB1 + t] = gb1[t]; s[S_AB1 + t] = ab1[t]; }
    if (t < 16)  { s[S_UB1 + t] = ub1[t]; }
    if (t < 3)   { s[S_GB2 + t] = gb2[t]; s[S_AB2 + t] = ab2[t]; }
    if (t < 6)   { s[S_UB2 + t] = ub2[t]; }
    __syncthreads();

    const long p = (long)blockIdx.x * 256 + t;   // < B*T exactly
    const long base = p * 6;
    float m0 = out[base+0], m1 = out[base+1], m2 = out[base+2];
    float m3 = out[base+3], m4 = out[base+4], m5 = out[base+5];

    float gy0 = s[S_GB2+0], gy1 = s[S_GB2+1], gy2 = s[S_GB2+2];
    float ac0 = s[S_AB2+0], ac1 = s[S_AB2+1], ac2 = s[S_AB2+2];
    #pragma unroll
    for (int i = 0; i < 32; ++i) {
        float hg = s[S_GB1+i] + s[S_GW1+i*6+0]*m0 + s[S_GW1+i*6+1]*m1
                 + s[S_GW1+i*6+2]*m2 + s[S_GW1+i*6+3]*m3
                 + s[S_GW1+i*6+4]*m4 + s[S_GW1+i*6+5]*m5;
        hg = ftanh(hg);
        gy0 += s[S_GW2+i]*hg; gy1 += s[S_GW2+32+i]*hg; gy2 += s[S_GW2+64+i]*hg;
        float ha = s[S_AB1+i] + s[S_AW1+i*6+0]*m0 + s[S_AW1+i*6+1]*m1
                 + s[S_AW1+i*6+2]*m2 + s[S_AW1+i*6+3]*m3
                 + s[S_AW1+i*6+4]*m4 + s[S_AW1+i*6+5]*m5;
        ha = ftanh(ha);
        ac0 += s[S_AW2+i]*ha; ac1 += s[S_AW2+32+i]*ha; ac2 += s[S_AW2+64+i]*ha;
    }
    float u0 = s[S_UB2+0], u1 = s[S_UB2+1], u2 = s[S_UB2+2];
    float u3 = s[S_UB2+3], u4 = s[S_UB2+4], u5 = s[S_UB2+5];
    #pragma unroll
    for (int i = 0; i < 16; ++i) {
        float hu = s[S_UB1+i] + s[S_UW1+i*6+0]*m0 + s[S_UW1+i*6+1]*m1
                 + s[S_UW1+i*6+2]*m2 + s[S_UW1+i*6+3]*m3
                 + s[S_UW1+i*6+4]*m4 + s[S_UW1+i*6+5]*m5;
        hu = fmaxf(hu, 0.f);
        u0 += s[S_UW2+i]*hu;      u1 += s[S_UW2+16+i]*hu; u2 += s[S_UW2+32+i]*hu;
        u3 += s[S_UW2+48+i]*hu;   u4 += s[S_UW2+64+i]*hu; u5 += s[S_UW2+80+i]*hu;
    }
    out[base+0] = gy0; out[base+1] = gy1; out[base+2] = gy2;
    out[base+3] = ac0; out[base+4] = ac1; out[base+5] = ac2;
    const long uoff = (long)BATCH * TSTEPS * 6;
    out[uoff+base+0] = fsoftplus(u0); out[uoff+base+1] = fsoftplus(u1);
    out[uoff+base+2] = fsoftplus(u2); out[uoff+base+3] = fsoftplus(u3);
    out[uoff+base+4] = fsoftplus(u4); out[uoff+base+5] = fsoftplus(u5);
}

extern "C" void kernel_launch(void* const* d_in, const int* in_sizes, int n_in,
                              void* d_out, int out_size, void* d_ws, size_t ws_size,
                              hipStream_t stream) {
    const float* x       = (const float*)d_in[0];
    const float* lstm_wi = (const float*)d_in[1];
    const float* lstm_wh = (const float*)d_in[2];
    const float* lstm_b  = (const float*)d_in[3];
    const float* c0w1 = (const float*)d_in[4];
    const float* c0w2 = (const float*)d_in[5];
    const float* c0wa = (const float*)d_in[6];
    const float* c0wb = (const float*)d_in[7];
    const float* c0b1 = (const float*)d_in[8];
    const float* c0b2 = (const float*)d_in[9];
    const float* c0ba = (const float*)d_in[10];
    const float* c0bb = (const float*)d_in[11];
    const float* c1w1 = (const float*)d_in[12];
    const float* c1w2 = (const float*)d_in[13];
    const float* c1wa = (const float*)d_in[14];
    const float* c1wb = (const float*)d_in[15];
    const float* c1b1 = (const float*)d_in[16];
    const float* c1b2 = (const float*)d_in[17];
    const float* c1ba = (const float*)d_in[18];
    const float* c1bb = (const float*)d_in[19];
    const float* c2w1 = (const float*)d_in[20];
    const float* c2w2 = (const float*)d_in[21];
    const float* c2wa = (const float*)d_in[22];
    const float* c2wb = (const float*)d_in[23];
    const float* c2b1 = (const float*)d_in[24];
    const float* c2b2 = (const float*)d_in[25];
    const float* c2ba = (const float*)d_in[26];
    const float* c2bb = (const float*)d_in[27];
    const float* gw1 = (const float*)d_in[28];
    const float* gb1 = (const float*)d_in[29];
    const float* gw2 = (const float*)d_in[30];
    const float* gb2 = (const float*)d_in[31];
    const float* aw1 = (const float*)d_in[32];
    const float* ab1 = (const float*)d_in[33];
    const float* aw2 = (const float*)d_in[34];
    const float* ab2 = (const float*)d_in[35];
    const float* uw1 = (const float*)d_in[36];
    const float* ub1 = (const float*)d_in[37];
    const float* uw2 = (const float*)d_in[38];
    const float* ub2 = (const float*)d_in[39];
    float* out = (float*)d_out;

    rnn_kernel<<<BATCH, 256, 0, stream>>>(x, lstm_wi, lstm_wh, lstm_b,
        c0w1, c0w2, c0wa, c0wb, c0b1, c0b2, c0ba, c0bb,
        c1w1, c1w2, c1wa, c1wb, c1b1, c1b2, c1ba, c1bb,
        c2w1, c2w2, c2wa, c2wb, c2b1, c2b2, c2ba, c2bb, out);

    head_kernel<<<(BATCH * TSTEPS) / 256, 256, 0, stream>>>(
        gw1, gb1, gw2, gb2, aw1, ab1, aw2, ab2, uw1, ub1, uw2, ub2, out);
}

// Round 3
// 8412.582 us; speedup vs baseline: 1.0868x; 1.0868x over previous
//
#include <hip/hip_runtime.h>
#include <math.h>

#define BATCH 128
#define TSTEPS 4096
#define INDIM 13

// Shared memory layout (one 224-float block, zero-initialized each launch):
//  zL[0:80]  = smem+0    [x(13) | o0(35) | o1(23) | o2(6) | pad(3)]  LSTM input
//  z0[0:48]  = smem+80   [x(13) | h0_lstm(35)]                       CfC0 input
//  z1[0:60]  = smem+128  [o0(35) | h1_lstm(23) | pad(2)]             CfC1 input
//  z2[0:32]  = smem+188  [o1(23) | h2_lstm(6) | pad(3)]              CfC2 input

__device__ __forceinline__ float fsig(float x) {
    return __builtin_amdgcn_rcpf(1.f + __expf(-x));
}
__device__ __forceinline__ float ftanh(float x) {
    float s = fsig(x + x);
    return s + s - 1.f;
}
__device__ __forceinline__ float fsoftplus(float x) {
    return (x > 15.f) ? x : __logf(1.f + __expf(x));
}

// Gather the 4 values of this lane-quad. Lane with (t&3)==sel owns value sel.
__device__ __forceinline__ void quad_gather(float own, int sel,
                                            float& v0, float& v1,
                                            float& v2, float& v3) {
    float b = __shfl_xor(own, 1, 64);
    float c = __shfl_xor(own, 2, 64);
    float d = __shfl_xor(b,   2, 64);
    v0 = (sel==0)?own:(sel==1)?b  :(sel==2)?c  :d;
    v1 = (sel==0)?b  :(sel==1)?own:(sel==2)?d  :c;
    v2 = (sel==0)?c  :(sel==1)?d  :(sel==2)?own:b;
    v3 = (sel==0)?d  :(sel==1)?c  :(sel==2)?b  :own;
}

__global__ __launch_bounds__(256, 1)
void rnn_kernel(const float* __restrict__ x,
                const float* __restrict__ lstm_wi, const float* __restrict__ lstm_wh,
                const float* __restrict__ lstm_b,
                const float* __restrict__ c0w1, const float* __restrict__ c0w2,
                const float* __restrict__ c0wa, const float* __restrict__ c0wb,
                const float* __restrict__ c0b1, const float* __restrict__ c0b2,
                const float* __restrict__ c0ba, const float* __restrict__ c0bb,
                const float* __restrict__ c1w1, const float* __restrict__ c1w2,
                const float* __restrict__ c1wa, const float* __restrict__ c1wb,
                const float* __restrict__ c1b1, const float* __restrict__ c1b2,
                const float* __restrict__ c1ba, const float* __restrict__ c1bb,
                const float* __restrict__ c2w1, const float* __restrict__ c2w2,
                const float* __restrict__ c2wa, const float* __restrict__ c2wb,
                const float* __restrict__ c2b1, const float* __restrict__ c2b2,
                const float* __restrict__ c2ba, const float* __restrict__ c2bb,
                float* __restrict__ out)
{
    const int bb = blockIdx.x;
    const int t  = threadIdx.x;
    const int g  = t & 3;      // quad slot: gate / branch type
    const int u  = t >> 2;     // quad index: unit index

    __shared__ __align__(16) float smem[224];
    float* zL = smem;
    float* z0 = smem + 80;
    float* z1 = smem + 128;
    float* z2 = smem + 188;

    const long xbase = (long)bb * TSTEPS * INDIM;
    const long obase = (long)bb * TSTEPS * 6;

    // ---- LSTM weights: 20 named float4 values (no alloca -> registers) ----
    const int r = g * 64 + u;          // gate-row in [ia;ig;fg;og] blocks
    auto lw = [&](int k) -> float {
        return (k < 13) ? lstm_wi[r * 13 + k]
             : (k < 77) ? lstm_wh[r * 64 + (k - 13)] : 0.f;
    };
    float4 wl0,wl1,wl2,wl3,wl4,wl5,wl6,wl7,wl8,wl9,
           wl10,wl11,wl12,wl13,wl14,wl15,wl16,wl17,wl18,wl19;
#define LDWL(i) wl##i = make_float4(lw(4*i+0), lw(4*i+1), lw(4*i+2), lw(4*i+3))
    LDWL(0);LDWL(1);LDWL(2);LDWL(3);LDWL(4);LDWL(5);LDWL(6);LDWL(7);LDWL(8);LDWL(9);
    LDWL(10);LDWL(11);LDWL(12);LDWL(13);LDWL(14);LDWL(15);LDWL(16);LDWL(17);LDWL(18);LDWL(19);
#undef LDWL
    const float bLr = lstm_b[r];

    // ---- CfC weights: 15 named float4 values, group-overlaid ----
    // grp0: t<140   -> CfC0 row u     (len 48, 12 chunks)
    // grp1: t<232   -> CfC1 row u-35  (len 58, 15 chunks)
    // grp2: t>=232  -> CfC2 row u-58  (len 29,  8 chunks)
    const int grp = (t < 140) ? 0 : (t < 232) ? 1 : 2;
    const int row = (grp == 0) ? u : (grp == 1) ? (u - 35) : (u - 58);
    const int rl  = (grp == 0) ? 48 : (grp == 1) ? 58 : 29;
    const float* Wp;
    float bCr;
    if (grp == 0) {
        Wp  = (g==0?c0w1:g==1?c0w2:g==2?c0wa:c0wb) + row * 48;
        bCr = (g==0?c0b1:g==1?c0b2:g==2?c0ba:c0bb)[row];
    } else if (grp == 1) {
        Wp  = (g==0?c1w1:g==1?c1w2:g==2?c1wa:c1wb) + row * 58;
        bCr = (g==0?c1b1:g==1?c1b2:g==2?c1ba:c1bb)[row];
    } else {
        Wp  = (g==0?c2w1:g==1?c2w2:g==2?c2wa:c2wb) + row * 29;
        bCr = (g==0?c2b1:g==1?c2b2:g==2?c2ba:c2bb)[row];
    }
    auto cwf = [&](int k) -> float { return (k < rl) ? Wp[k] : 0.f; };
    float4 wc0,wc1,wc2,wc3,wc4,wc5,wc6,wc7,wc8,wc9,wc10,wc11,wc12,wc13,wc14;
#define LDWC(i) wc##i = make_float4(cwf(4*i+0), cwf(4*i+1), cwf(4*i+2), cwf(4*i+3))
    LDWC(0);LDWC(1);LDWC(2);LDWC(3);LDWC(4);LDWC(5);LDWC(6);LDWC(7);
    LDWC(8);LDWC(9);LDWC(10);LDWC(11);LDWC(12);LDWC(13);LDWC(14);
#undef LDWC

    const bool pfl = (t >= 96 && t < 109);  // x-prefetch lanes (grp0, idle in ph4)
    float creg = 0.f;                        // cell state, replicated per quad

    // ---- init LDS: zero everything, then x_0 ----
    if (t >= 13 && t < 224) smem[t] = 0.f;
    if (t < 13)             zL[t] = x[xbase + t];
    __syncthreads();

#define DOTF(A, W, i, zz) { float4 _zv = *(const float4*)&zz[4*i];       \
    A.x += _zv.x * W##i.x; A.y += _zv.y * W##i.y;                        \
    A.z += _zv.z * W##i.z; A.w += _zv.w * W##i.w; }

    #pragma unroll 1
    for (int ts = 0; ts < TSTEPS; ++ts) {
        // ---- phase 1: LSTM (all 256 threads) ----
        float xn = 0.f;
        if (pfl && (ts + 1) < TSTEPS)
            xn = x[xbase + (long)(ts + 1) * 13 + (t - 96)];
        if (g == 1 && u < 13) z0[u] = zL[u];   // copy x_t into CfC0 input

        float4 aL = make_float4(0.f, 0.f, 0.f, 0.f);
        DOTF(aL, wl, 0, zL) DOTF(aL, wl, 1, zL) DOTF(aL, wl, 2, zL)
        DOTF(aL, wl, 3, zL) DOTF(aL, wl, 4, zL) DOTF(aL, wl, 5, zL)
        DOTF(aL, wl, 6, zL) DOTF(aL, wl, 7, zL) DOTF(aL, wl, 8, zL)
        DOTF(aL, wl, 9, zL) DOTF(aL, wl,10, zL) DOTF(aL, wl,11, zL)
        DOTF(aL, wl,12, zL) DOTF(aL, wl,13, zL) DOTF(aL, wl,14, zL)
        DOTF(aL, wl,15, zL) DOTF(aL, wl,16, zL) DOTF(aL, wl,17, zL)
        DOTF(aL, wl,18, zL) DOTF(aL, wl,19, zL)
        float dL = (aL.x + aL.y) + (aL.z + aL.w) + bLr;
        float iav, igv, fgv, ogv;
        quad_gather(dL, g, iav, igv, fgv, ogv);
        float cn = creg * fsig(fgv + 1.f) + ftanh(iav) * fsig(igv);
        creg = cn;                              // identical on all 4 quad lanes
        float hl = ftanh(cn) * fsig(ogv);
        if (g == 0) {
            if (u < 35)      z0[13 + u] = hl;   // h0
            else if (u < 58) z1[u]      = hl;   // h1 at z1[35..57]
            else             z2[u - 35] = hl;   // h2 at z2[23..28]
        }
        __syncthreads();

        // ---- phase 2: CfC layer 0 (grp0: 12 chunks over z0) ----
        if (grp == 0) {
            float4 a2 = make_float4(0.f, 0.f, 0.f, 0.f);
            DOTF(a2, wc, 0, z0) DOTF(a2, wc, 1, z0) DOTF(a2, wc, 2, z0)
            DOTF(a2, wc, 3, z0) DOTF(a2, wc, 4, z0) DOTF(a2, wc, 5, z0)
            DOTF(a2, wc, 6, z0) DOTF(a2, wc, 7, z0) DOTF(a2, wc, 8, z0)
            DOTF(a2, wc, 9, z0) DOTF(a2, wc,10, z0) DOTF(a2, wc,11, z0)
            float dd = (a2.x + a2.y) + (a2.z + a2.w) + bCr;
            float f1d, f2d, tad, tbd;
            quad_gather(dd, g, f1d, f2d, tad, tbd);
            if (g == 0) {
                float tg = fsig(tad + tbd);
                float f1 = ftanh(f1d), f2 = ftanh(f2d);
                float o = f1 + tg * (f2 - f1);
                z1[row] = o;          // input to CfC1
                zL[13 + row] = o;     // new h[0:35]
            }
        }
        __syncthreads();

        // ---- phase 3: CfC layer 1 (grp1: 15 chunks over z1) ----
        if (grp == 1) {
            float4 a3 = make_float4(0.f, 0.f, 0.f, 0.f);
            DOTF(a3, wc, 0, z1) DOTF(a3, wc, 1, z1) DOTF(a3, wc, 2, z1)
            DOTF(a3, wc, 3, z1) DOTF(a3, wc, 4, z1) DOTF(a3, wc, 5, z1)
            DOTF(a3, wc, 6, z1) DOTF(a3, wc, 7, z1) DOTF(a3, wc, 8, z1)
            DOTF(a3, wc, 9, z1) DOTF(a3, wc,10, z1) DOTF(a3, wc,11, z1)
            DOTF(a3, wc,12, z1) DOTF(a3, wc,13, z1) DOTF(a3, wc,14, z1)
            float dd = (a3.x + a3.y) + (a3.z + a3.w) + bCr;
            float f1d, f2d, tad, tbd;
            quad_gather(dd, g, f1d, f2d, tad, tbd);
            if (g == 0) {
                float tg = fsig(tad + tbd);
                float f1 = ftanh(f1d), f2 = ftanh(f2d);
                float o = f1 + tg * (f2 - f1);
                z2[row] = o;          // input to CfC2
                zL[48 + row] = o;     // new h[35:58]
            }
        }
        __syncthreads();

        // ---- phase 4: CfC layer 2 (grp2: 8 chunks over z2) + x commit ----
        if (grp == 2) {
            float4 a4 = make_float4(0.f, 0.f, 0.f, 0.f);
            DOTF(a4, wc, 0, z2) DOTF(a4, wc, 1, z2) DOTF(a4, wc, 2, z2)
            DOTF(a4, wc, 3, z2) DOTF(a4, wc, 4, z2) DOTF(a4, wc, 5, z2)
            DOTF(a4, wc, 6, z2) DOTF(a4, wc, 7, z2)
            float dd = (a4.x + a4.y) + (a4.z + a4.w) + bCr;
            float f1d, f2d, tad, tbd;
            quad_gather(dd, g, f1d, f2d, tad, tbd);
            if (g == 0) {
                float tg = fsig(tad + tbd);
                float f1 = ftanh(f1d), f2 = ftanh(f2d);
                float o = f1 + tg * (f2 - f1);
                out[obase + (long)ts * 6 + row] = o;  // raw cfc_out
                zL[71 + row] = o;                     // new h[58:64]
            }
        } else if (pfl) {
            zL[t - 96] = xn;                          // commit x_{t+1}
        }
        __syncthreads();
    }
#undef DOTF
}

// ---- head: rewrite pred in place, write unc ----
#define S_GW1 0
#define S_GB1 192
#define S_GW2 224
#define S_GB2 320
#define S_AW1 323
#define S_AB1 515
#define S_AW2 547
#define S_AB2 643
#define S_UW1 646
#define S_UB1 742
#define S_UW2 758
#define S_UB2 854
#define S_TOT 860

__global__ __launch_bounds__(256)
void head_kernel(const float* __restrict__ gw1, const float* __restrict__ gb1,
                 const float* __restrict__ gw2, const float* __restrict__ gb2,
                 const float* __restrict__ aw1, const float* __restrict__ ab1,
                 const float* __restrict__ aw2, const float* __restrict__ ab2,
                 const float* __restrict__ uw1, const float* __restrict__ ub1,
                 const float* __restrict__ uw2, const float* __restrict__ ub2,
                 float* __restrict__ out)
{
    __shared__ float s[S_TOT];
    const int t = threadIdx.x;
    if (t < 192) { s[S_GW1 + t] = gw1[t]; s[S_AW1 + t] = aw1[t]; }
    if (t < 96)  { s[S_GW2 + t] = gw2[t]; s[S_AW2 + t] = aw2[t];
                   s[S_UW1 + t] = uw1[t]; s[S_UW2 + t] = uw2[t]; }
    if (t < 32)  { s[S_GB1 + t] = gb1[t]; s[S_AB1 + t] = ab1[t]; }
    if (t < 16)  { s[S_UB1 + t] = ub1[t]; }
    if (t < 3)   { s[S_GB2 + t] = gb2[t]; s[S_AB2 + t] = ab2[t]; }
    if (t < 6)   { s[S_UB2 + t] = ub2[t]; }
    __syncthreads();

    const long p = (long)blockIdx.x * 256 + t;   // < B*T exactly
    const long base = p * 6;
    float m0 = out[base+0], m1 = out[base+1], m2 = out[base+2];
    float m3 = out[base+3], m4 = out[base+4], m5 = out[base+5];

    float gy0 = s[S_GB2+0], gy1 = s[S_GB2+1], gy2 = s[S_GB2+2];
    float ac0 = s[S_AB2+0], ac1 = s[S_AB2+1], ac2 = s[S_AB2+2];
    #pragma unroll
    for (int i = 0; i < 32; ++i) {
        float hg = s[S_GB1+i] + s[S_GW1+i*6+0]*m0 + s[S_GW1+i*6+1]*m1
                 + s[S_GW1+i*6+2]*m2 + s[S_GW1+i*6+3]*m3
                 + s[S_GW1+i*6+4]*m4 + s[S_GW1+i*6+5]*m5;
        hg = ftanh(hg);
        gy0 += s[S_GW2+i]*hg; gy1 += s[S_GW2+32+i]*hg; gy2 += s[S_GW2+64+i]*hg;
        float ha = s[S_AB1+i] + s[S_AW1+i*6+0]*m0 + s[S_AW1+i*6+1]*m1
                 + s[S_AW1+i*6+2]*m2 + s[S_AW1+i*6+3]*m3
                 + s[S_AW1+i*6+4]*m4 + s[S_AW1+i*6+5]*m5;
        ha = ftanh(ha);
        ac0 += s[S_AW2+i]*ha; ac1 += s[S_AW2+32+i]*ha; ac2 += s[S_AW2+64+i]*ha;
    }
    float u0 = s[S_UB2+0], u1 = s[S_UB2+1], u2 = s[S_UB2+2];
    float u3 = s[S_UB2+3], u4 = s[S_UB2+4], u5 = s[S_UB2+5];
    #pragma unroll
    for (int i = 0; i < 16; ++i) {
        float hu = s[S_UB1+i] + s[S_UW1+i*6+0]*m0 + s[S_UW1+i*6+1]*m1
                 + s[S_UW1+i*6+2]*m2 + s[S_UW1+i*6+3]*m3
                 + s[S_UW1+i*6+4]*m4 + s[S_UW1+i*6+5]*m5;
        hu = fmaxf(hu, 0.f);
        u0 += s[S_UW2+i]*hu;      u1 += s[S_UW2+16+i]*hu; u2 += s[S_UW2+32+i]*hu;
        u3 += s[S_UW2+48+i]*hu;   u4 += s[S_UW2+64+i]*hu; u5 += s[S_UW2+80+i]*hu;
    }
    out[base+0] = gy0; out[base+1] = gy1; out[base+2] = gy2;
    out[base+3] = ac0; out[base+4] = ac1; out[base+5] = ac2;
    const long uoff = (long)BATCH * TSTEPS * 6;
    out[uoff+base+0] = fsoftplus(u0); out[uoff+base+1] = fsoftplus(u1);
    out[uoff+base+2] = fsoftplus(u2); out[uoff+base+3] = fsoftplus(u3);
    out[uoff+base+4] = fsoftplus(u4); out[uoff+base+5] = fsoftplus(u5);
}

extern "C" void kernel_launch(void* const* d_in, const int* in_sizes, int n_in,
                              void* d_out, int out_size, void* d_ws, size_t ws_size,
                              hipStream_t stream) {
    const float* x       = (const float*)d_in[0];
    const float* lstm_wi = (const float*)d_in[1];
    const float* lstm_wh = (const float*)d_in[2];
    const float* lstm_b  = (const float*)d_in[3];
    const float* c0w1 = (const float*)d_in[4];
    const float* c0w2 = (const float*)d_in[5];
    const float* c0wa = (const float*)d_in[6];
    const float* c0wb = (const float*)d_in[7];
    const float* c0b1 = (const float*)d_in[8];
    const float* c0b2 = (const float*)d_in[9];
    const float* c0ba = (const float*)d_in[10];
    const float* c0bb = (const float*)d_in[11];
    const float* c1w1 = (const float*)d_in[12];
    const float* c1w2 = (const float*)d_in[13];
    const float* c1wa = (const float*)d_in[14];
    const float* c1wb = (const float*)d_in[15];
    const float* c1b1 = (const float*)d_in[16];
    const float* c1b2 = (const float*)d_in[17];
    const float* c1ba = (const float*)d_in[18];
    const float* c1bb = (const float*)d_in[19];
    const float* c2w1 = (const float*)d_in[20];
    const float* c2w2 = (const float*)d_in[21];
    const float* c2wa = (const float*)d_in[22];
    const float* c2wb = (const float*)d_in[23];
    const float* c2b1 = (const float*)d_in[24];
    const float* c2b2 = (const float*)d_in[25];
    const float* c2ba = (const float*)d_in[26];
    const float* c2bb = (const float*)d_in[27];
    const float* gw1 = (const float*)d_in[28];
    const float* gb1 = (const float*)d_in[29];
    const float* gw2 = (const float*)d_in[30];
    const float* gb2 = (const float*)d_in[31];
    const float* aw1 = (const float*)d_in[32];
    const float* ab1 = (const float*)d_in[33];
    const float* aw2 = (const float*)d_in[34];
    const float* ab2 = (const float*)d_in[35];
    const float* uw1 = (const float*)d_in[36];
    const float* ub1 = (const float*)d_in[37];
    const float* uw2 = (const float*)d_in[38];
    const float* ub2 = (const float*)d_in[39];
    float* out = (float*)d_out;

    rnn_kernel<<<BATCH, 256, 0, stream>>>(x, lstm_wi, lstm_wh, lstm_b,
        c0w1, c0w2, c0wa, c0wb, c0b1, c0b2, c0ba, c0bb,
        c1w1, c1w2, c1wa, c1wb, c1b1, c1b2, c1ba, c1bb,
        c2w1, c2w2, c2wa, c2wb, c2b1, c2b2, c2ba, c2bb, out);

    head_kernel<<<(BATCH * TSTEPS) / 256, 256, 0, stream>>>(
        gw1, gb1, gw2, gb2, aw1, ab1, aw2, ab2, uw1, ub1, uw2, ub2, out);
}

// Round 4
// 6448.251 us; speedup vs baseline: 1.4179x; 1.3046x over previous
//
#include <hip/hip_runtime.h>
#include <math.h>

#define BATCH 128
#define TSTEPS 4096
#define INDIM 13

// Shared memory layout (224 floats, zero-initialized each launch):
//  zL[0:80]  = smem+0    [x(13) | o0(35) | o1(23) | o2(6) | pad(3)]  LSTM input
//  z0[0:48]  = smem+80   [x(13) | h0_lstm(35)]                       CfC0 input
//  z1[0:64]  = smem+128  [o0(35) | h1_lstm(23) | pad(6)]             CfC1 input
//  z2[0:32]  = smem+192  [o1(23) | h2_lstm(6) | pad(3)]              CfC2 input

__device__ __forceinline__ float fsig(float x) {
    return __builtin_amdgcn_rcpf(1.f + __expf(-x));
}
__device__ __forceinline__ float ftanh(float x) {
    float s = fsig(x + x);
    return s + s - 1.f;
}
__device__ __forceinline__ float fsoftplus(float x) {
    return (x > 15.f) ? x : __logf(1.f + __expf(x));
}

// quad butterfly allreduce (bit-identical on all 4 lanes of the quad)
#define BFLY(a) { a += __shfl_xor(a, 1, 64); a += __shfl_xor(a, 2, 64); }

// acc += dot(float4 zv, 4 named weight scalars W_q_{0..3})
#define FMA4(acc, W, q, zv) { acc += zv.x * W##_##q##_0; acc += zv.y * W##_##q##_1; \
                              acc += zv.z * W##_##q##_2; acc += zv.w * W##_##q##_3; }

__global__ __attribute__((amdgpu_flat_work_group_size(256, 256),
                          amdgpu_waves_per_eu(1, 1)))
void rnn_kernel(const float* __restrict__ x,
                const float* __restrict__ lstm_wi, const float* __restrict__ lstm_wh,
                const float* __restrict__ lstm_b,
                const float* __restrict__ c0w1, const float* __restrict__ c0w2,
                const float* __restrict__ c0wa, const float* __restrict__ c0wb,
                const float* __restrict__ c0b1, const float* __restrict__ c0b2,
                const float* __restrict__ c0ba, const float* __restrict__ c0bb,
                const float* __restrict__ c1w1, const float* __restrict__ c1w2,
                const float* __restrict__ c1wa, const float* __restrict__ c1wb,
                const float* __restrict__ c1b1, const float* __restrict__ c1b2,
                const float* __restrict__ c1ba, const float* __restrict__ c1bb,
                const float* __restrict__ c2w1, const float* __restrict__ c2w2,
                const float* __restrict__ c2wa, const float* __restrict__ c2wb,
                const float* __restrict__ c2b1, const float* __restrict__ c2b2,
                const float* __restrict__ c2ba, const float* __restrict__ c2bb,
                float* __restrict__ out)
{
    const int bb = blockIdx.x;
    const int t  = threadIdx.x;
    const int g  = t & 3;      // K-chunk slot within the quad
    const int u  = t >> 2;     // unit / row-group index

    __shared__ __align__(16) float smem[224];
    float* zL = smem;
    float* z0 = smem + 80;
    float* z1 = smem + 128;
    float* z2 = smem + 192;

    const long xbase = (long)bb * TSTEPS * INDIM;
    const long obase = (long)bb * TSTEPS * 6;

    // ---- LSTM weights: lane (u,g) holds chunk [20g,20g+20) of ALL 4 gate rows
    // of unit u. 80 individually-named scalars (no arrays -> no SROA/align issues).
    auto lwf = [&](int A, int c) -> float {
        int r = A * 64 + u;
        return (c < 13) ? lstm_wi[r * 13 + c]
             : (c < 77) ? lstm_wh[r * 64 + (c - 13)] : 0.f;
    };
#define DEF_WL(A,q) \
    float wl##A##_##q##_0 = lwf(A, 20*g + 4*q + 0); \
    float wl##A##_##q##_1 = lwf(A, 20*g + 4*q + 1); \
    float wl##A##_##q##_2 = lwf(A, 20*g + 4*q + 2); \
    float wl##A##_##q##_3 = lwf(A, 20*g + 4*q + 3);
    DEF_WL(0,0) DEF_WL(0,1) DEF_WL(0,2) DEF_WL(0,3) DEF_WL(0,4)
    DEF_WL(1,0) DEF_WL(1,1) DEF_WL(1,2) DEF_WL(1,3) DEF_WL(1,4)
    DEF_WL(2,0) DEF_WL(2,1) DEF_WL(2,2) DEF_WL(2,3) DEF_WL(2,4)
    DEF_WL(3,0) DEF_WL(3,1) DEF_WL(3,2) DEF_WL(3,3) DEF_WL(3,4)
#undef DEF_WL
    const float bL0 = lstm_b[u];
    const float bL1 = lstm_b[64 + u];
    const float bL2 = lstm_b[128 + u];
    const float bL3 = lstm_b[192 + u];

    // ---- CfC weights: lane (u,g) holds chunk g of ALL 4 branch rows of its
    // group's row. Groups are disjoint lane sets; one shared 64-name overlay.
    // grp0 (t<140): row u,  len 48, chunk 12 (quads 0..2)
    // grp1 (t<232): row u-35, len 58->64, chunk 16 (quads 0..3)
    // grp2 (rest):  row u-58, len 29->32, chunk 8  (quads 0..1)
    const int grp = (t < 140) ? 0 : (t < 232) ? 1 : 2;
    const int row = (grp == 0) ? u : (grp == 1) ? (u - 35) : (u - 58);
    const int rl  = (grp == 0) ? 48 : (grp == 1) ? 58 : 29;
    const int cb  = (grp == 0) ? 12 * g : (grp == 1) ? 16 * g : 8 * g;
    const float *W0p, *W1p, *W2p, *W3p;
    float bC0, bC1, bC2, bC3;
    if (grp == 0) {
        W0p = c0w1 + row * 48; W1p = c0w2 + row * 48;
        W2p = c0wa + row * 48; W3p = c0wb + row * 48;
        bC0 = c0b1[row]; bC1 = c0b2[row]; bC2 = c0ba[row]; bC3 = c0bb[row];
    } else if (grp == 1) {
        W0p = c1w1 + row * 58; W1p = c1w2 + row * 58;
        W2p = c1wa + row * 58; W3p = c1wb + row * 58;
        bC0 = c1b1[row]; bC1 = c1b2[row]; bC2 = c1ba[row]; bC3 = c1bb[row];
    } else {
        W0p = c2w1 + row * 29; W1p = c2w2 + row * 29;
        W2p = c2wa + row * 29; W3p = c2wb + row * 29;
        bC0 = c2b1[row]; bC1 = c2b2[row]; bC2 = c2ba[row]; bC3 = c2bb[row];
    }
    auto cwf = [&](const float* W, int c) -> float {
        int cc = cb + c;
        return (cc < rl) ? W[cc] : 0.f;
    };
#define DEF_WC(A,q) \
    float wc##A##_##q##_0 = cwf(W##A##p, 4*q + 0); \
    float wc##A##_##q##_1 = cwf(W##A##p, 4*q + 1); \
    float wc##A##_##q##_2 = cwf(W##A##p, 4*q + 2); \
    float wc##A##_##q##_3 = cwf(W##A##p, 4*q + 3);
    DEF_WC(0,0) DEF_WC(0,1) DEF_WC(0,2) DEF_WC(0,3)
    DEF_WC(1,0) DEF_WC(1,1) DEF_WC(1,2) DEF_WC(1,3)
    DEF_WC(2,0) DEF_WC(2,1) DEF_WC(2,2) DEF_WC(2,3)
    DEF_WC(3,0) DEF_WC(3,1) DEF_WC(3,2) DEF_WC(3,3)
#undef DEF_WC

    const bool pfl = (t >= 96 && t < 109);  // x-prefetch lanes (grp0, idle in ph4)
    float creg = 0.f;                        // cell state, replicated per quad

    // ---- init LDS: zero everything, then x_0 ----
    if (t >= 13 && t < 224) smem[t] = 0.f;
    if (t < 13)             zL[t] = x[xbase + t];
    __syncthreads();

    #pragma unroll 1
    for (int ts = 0; ts < TSTEPS; ++ts) {
        // ---- phase 1: LSTM (all 256 lanes; K-split by g) ----
        float xn = 0.f;
        if (pfl && (ts + 1) < TSTEPS)
            xn = x[xbase + (long)(ts + 1) * 13 + (t - 96)];
        if (g == 1 && u < 13) z0[u] = zL[u];   // copy x_t into CfC0 input
        {
            const float4* zc = (const float4*)(zL + 20 * g);
            float4 q0 = zc[0], q1 = zc[1], q2 = zc[2], q3 = zc[3], q4 = zc[4];
            float a0 = 0.f, a1 = 0.f, a2 = 0.f, a3 = 0.f;
            FMA4(a0, wl0, 0, q0) FMA4(a0, wl0, 1, q1) FMA4(a0, wl0, 2, q2)
            FMA4(a0, wl0, 3, q3) FMA4(a0, wl0, 4, q4)
            FMA4(a1, wl1, 0, q0) FMA4(a1, wl1, 1, q1) FMA4(a1, wl1, 2, q2)
            FMA4(a1, wl1, 3, q3) FMA4(a1, wl1, 4, q4)
            FMA4(a2, wl2, 0, q0) FMA4(a2, wl2, 1, q1) FMA4(a2, wl2, 2, q2)
            FMA4(a2, wl2, 3, q3) FMA4(a2, wl2, 4, q4)
            FMA4(a3, wl3, 0, q0) FMA4(a3, wl3, 1, q1) FMA4(a3, wl3, 2, q2)
            FMA4(a3, wl3, 3, q3) FMA4(a3, wl3, 4, q4)
            BFLY(a0) BFLY(a1) BFLY(a2) BFLY(a3)
            a0 += bL0; a1 += bL1; a2 += bL2; a3 += bL3;   // ia, ig, fg, og
            float cn = creg * fsig(a2 + 1.f) + ftanh(a0) * fsig(a1);
            creg = cn;                       // bit-identical on all 4 quad lanes
            float hl = ftanh(cn) * fsig(a3);
            if (g == 0) {
                if (u < 35)      z0[13 + u] = hl;   // h0
                else if (u < 58) z1[u]      = hl;   // h1 at z1[35..57]
                else             z2[u - 35] = hl;   // h2 at z2[23..28]
            }
        }
        __syncthreads();

        // ---- phase 2: CfC layer 0 (grp0; chunk 12 over z0) ----
        if (grp == 0) {
            const float4* zc = (const float4*)(z0 + 12 * g);
            float4 p0 = zc[0], p1 = zc[1], p2 = zc[2];
            float a0 = 0.f, a1 = 0.f, a2 = 0.f, a3 = 0.f;
            FMA4(a0, wc0, 0, p0) FMA4(a0, wc0, 1, p1) FMA4(a0, wc0, 2, p2)
            FMA4(a1, wc1, 0, p0) FMA4(a1, wc1, 1, p1) FMA4(a1, wc1, 2, p2)
            FMA4(a2, wc2, 0, p0) FMA4(a2, wc2, 1, p1) FMA4(a2, wc2, 2, p2)
            FMA4(a3, wc3, 0, p0) FMA4(a3, wc3, 1, p1) FMA4(a3, wc3, 2, p2)
            BFLY(a0) BFLY(a1) BFLY(a2) BFLY(a3)
            a0 += bC0; a1 += bC1; a2 += bC2; a3 += bC3;
            float tg = fsig(a2 + a3);
            float f1 = ftanh(a0), f2 = ftanh(a1);
            float o = f1 + tg * (f2 - f1);
            if (g == 0) { z1[row] = o; zL[13 + row] = o; }
        }
        __syncthreads();

        // ---- phase 3: CfC layer 1 (grp1; chunk 16 over z1) ----
        if (grp == 1) {
            const float4* zc = (const float4*)(z1 + 16 * g);
            float4 p0 = zc[0], p1 = zc[1], p2 = zc[2], p3 = zc[3];
            float a0 = 0.f, a1 = 0.f, a2 = 0.f, a3 = 0.f;
            FMA4(a0, wc0, 0, p0) FMA4(a0, wc0, 1, p1) FMA4(a0, wc0, 2, p2) FMA4(a0, wc0, 3, p3)
            FMA4(a1, wc1, 0, p0) FMA4(a1, wc1, 1, p1) FMA4(a1, wc1, 2, p2) FMA4(a1, wc1, 3, p3)
            FMA4(a2, wc2, 0, p0) FMA4(a2, wc2, 1, p1) FMA4(a2, wc2, 2, p2) FMA4(a2, wc2, 3, p3)
            FMA4(a3, wc3, 0, p0) FMA4(a3, wc3, 1, p1) FMA4(a3, wc3, 2, p2) FMA4(a3, wc3, 3, p3)
            BFLY(a0) BFLY(a1) BFLY(a2) BFLY(a3)
            a0 += bC0; a1 += bC1; a2 += bC2; a3 += bC3;
            float tg = fsig(a2 + a3);
            float f1 = ftanh(a0), f2 = ftanh(a1);
            float o = f1 + tg * (f2 - f1);
            if (g == 0) { z2[row] = o; zL[48 + row] = o; }
        }
        __syncthreads();

        // ---- phase 4: CfC layer 2 (grp2; chunk 8 over z2) + x commit ----
        if (grp == 2) {
            const float4* zc = (const float4*)(z2 + 8 * g);
            float4 p0 = zc[0], p1 = zc[1];
            float a0 = 0.f, a1 = 0.f, a2 = 0.f, a3 = 0.f;
            FMA4(a0, wc0, 0, p0) FMA4(a0, wc0, 1, p1)
            FMA4(a1, wc1, 0, p0) FMA4(a1, wc1, 1, p1)
            FMA4(a2, wc2, 0, p0) FMA4(a2, wc2, 1, p1)
            FMA4(a3, wc3, 0, p0) FMA4(a3, wc3, 1, p1)
            BFLY(a0) BFLY(a1) BFLY(a2) BFLY(a3)
            a0 += bC0; a1 += bC1; a2 += bC2; a3 += bC3;
            float tg = fsig(a2 + a3);
            float f1 = ftanh(a0), f2 = ftanh(a1);
            float o = f1 + tg * (f2 - f1);
            if (g == 0) {
                out[obase + (long)ts * 6 + row] = o;  // raw cfc_out
                zL[71 + row] = o;                     // new h[58:64]
            }
        } else if (pfl) {
            zL[t - 96] = xn;                          // commit x_{t+1}
        }
        __syncthreads();
    }
}

// ---- head: rewrite pred in place, write unc ----
#define S_GW1 0
#define S_GB1 192
#define S_GW2 224
#define S_GB2 320
#define S_AW1 323
#define S_AB1 515
#define S_AW2 547
#define S_AB2 643
#define S_UW1 646
#define S_UB1 742
#define S_UW2 758
#define S_UB2 854
#define S_TOT 860

__global__ __launch_bounds__(256)
void head_kernel(const float* __restrict__ gw1, const float* __restrict__ gb1,
                 const float* __restrict__ gw2, const float* __restrict__ gb2,
                 const float* __restrict__ aw1, const float* __restrict__ ab1,
                 const float* __restrict__ aw2, const float* __restrict__ ab2,
                 const float* __restrict__ uw1, const float* __restrict__ ub1,
                 const float* __restrict__ uw2, const float* __restrict__ ub2,
                 float* __restrict__ out)
{
    __shared__ float s[S_TOT];
    const int t = threadIdx.x;
    if (t < 192) { s[S_GW1 + t] = gw1[t]; s[S_AW1 + t] = aw1[t]; }
    if (t < 96)  { s[S_GW2 + t] = gw2[t]; s[S_AW2 + t] = aw2[t];
                   s[S_UW1 + t] = uw1[t]; s[S_UW2 + t] = uw2[t]; }
    if (t < 32)  { s[S_GB1 + t] = gb1[t]; s[S_AB1 + t] = ab1[t]; }
    if (t < 16)  { s[S_UB1 + t] = ub1[t]; }
    if (t < 3)   { s[S_GB2 + t] = gb2[t]; s[S_AB2 + t] = ab2[t]; }
    if (t < 6)   { s[S_UB2 + t] = ub2[t]; }
    __syncthreads();

    const long p = (long)blockIdx.x * 256 + t;   // < B*T exactly
    const long base = p * 6;
    float m0 = out[base+0], m1 = out[base+1], m2 = out[base+2];
    float m3 = out[base+3], m4 = out[base+4], m5 = out[base+5];

    float gy0 = s[S_GB2+0], gy1 = s[S_GB2+1], gy2 = s[S_GB2+2];
    float ac0 = s[S_AB2+0], ac1 = s[S_AB2+1], ac2 = s[S_AB2+2];
    #pragma unroll
    for (int i = 0; i < 32; ++i) {
        float hg = s[S_GB1+i] + s[S_GW1+i*6+0]*m0 + s[S_GW1+i*6+1]*m1
                 + s[S_GW1+i*6+2]*m2 + s[S_GW1+i*6+3]*m3
                 + s[S_GW1+i*6+4]*m4 + s[S_GW1+i*6+5]*m5;
        hg = ftanh(hg);
        gy0 += s[S_GW2+i]*hg; gy1 += s[S_GW2+32+i]*hg; gy2 += s[S_GW2+64+i]*hg;
        float ha = s[S_AB1+i] + s[S_AW1+i*6+0]*m0 + s[S_AW1+i*6+1]*m1
                 + s[S_AW1+i*6+2]*m2 + s[S_AW1+i*6+3]*m3
                 + s[S_AW1+i*6+4]*m4 + s[S_AW1+i*6+5]*m5;
        ha = ftanh(ha);
        ac0 += s[S_AW2+i]*ha; ac1 += s[S_AW2+32+i]*ha; ac2 += s[S_AW2+64+i]*ha;
    }
    float u0 = s[S_UB2+0], u1 = s[S_UB2+1], u2 = s[S_UB2+2];
    float u3 = s[S_UB2+3], u4 = s[S_UB2+4], u5 = s[S_UB2+5];
    #pragma unroll
    for (int i = 0; i < 16; ++i) {
        float hu = s[S_UB1+i] + s[S_UW1+i*6+0]*m0 + s[S_UW1+i*6+1]*m1
                 + s[S_UW1+i*6+2]*m2 + s[S_UW1+i*6+3]*m3
                 + s[S_UW1+i*6+4]*m4 + s[S_UW1+i*6+5]*m5;
        hu = fmaxf(hu, 0.f);
        u0 += s[S_UW2+i]*hu;      u1 += s[S_UW2+16+i]*hu; u2 += s[S_UW2+32+i]*hu;
        u3 += s[S_UW2+48+i]*hu;   u4 += s[S_UW2+64+i]*hu; u5 += s[S_UW2+80+i]*hu;
    }
    out[base+0] = gy0; out[base+1] = gy1; out[base+2] = gy2;
    out[base+3] = ac0; out[base+4] = ac1; out[base+5] = ac2;
    const long uoff = (long)BATCH * TSTEPS * 6;
    out[uoff+base+0] = fsoftplus(u0); out[uoff+base+1] = fsoftplus(u1);
    out[uoff+base+2] = fsoftplus(u2); out[uoff+base+3] = fsoftplus(u3);
    out[uoff+base+4] = fsoftplus(u4); out[uoff+base+5] = fsoftplus(u5);
}

extern "C" void kernel_launch(void* const* d_in, const int* in_sizes, int n_in,
                              void* d_out, int out_size, void* d_ws, size_t ws_size,
                              hipStream_t stream) {
    const float* x       = (const float*)d_in[0];
    const float* lstm_wi = (const float*)d_in[1];
    const float* lstm_wh = (const float*)d_in[2];
    const float* lstm_b  = (const float*)d_in[3];
    const float* c0w1 = (const float*)d_in[4];
    const float* c0w2 = (const float*)d_in[5];
    const float* c0wa = (const float*)d_in[6];
    const float* c0wb = (const float*)d_in[7];
    const float* c0b1 = (const float*)d_in[8];
    const float* c0b2 = (const float*)d_in[9];
    const float* c0ba = (const float*)d_in[10];
    const float* c0bb = (const float*)d_in[11];
    const float* c1w1 = (const float*)d_in[12];
    const float* c1w2 = (const float*)d_in[13];
    const float* c1wa = (const float*)d_in[14];
    const float* c1wb = (const float*)d_in[15];
    const float* c1b1 = (const float*)d_in[16];
    const float* c1b2 = (const float*)d_in[17];
    const float* c1ba = (const float*)d_in[18];
    const float* c1bb = (const float*)d_in[19];
    const float* c2w1 = (const float*)d_in[20];
    const float* c2w2 = (const float*)d_in[21];
    const float* c2wa = (const float*)d_in[22];
    const float* c2wb = (const float*)d_in[23];
    const float* c2b1 = (const float*)d_in[24];
    const float* c2b2 = (const float*)d_in[25];
    const float* c2ba = (const float*)d_in[26];
    const float* c2bb = (const float*)d_in[27];
    const float* gw1 = (const float*)d_in[28];
    const float* gb1 = (const float*)d_in[29];
    const float* gw2 = (const float*)d_in[30];
    const float* gb2 = (const float*)d_in[31];
    const float* aw1 = (const float*)d_in[32];
    const float* ab1 = (const float*)d_in[33];
    const float* aw2 = (const float*)d_in[34];
    const float* ab2 = (const float*)d_in[35];
    const float* uw1 = (const float*)d_in[36];
    const float* ub1 = (const float*)d_in[37];
    const float* uw2 = (const float*)d_in[38];
    const float* ub2 = (const float*)d_in[39];
    float* out = (float*)d_out;

    rnn_kernel<<<BATCH, 256, 0, stream>>>(x, lstm_wi, lstm_wh, lstm_b,
        c0w1, c0w2, c0wa, c0wb, c0b1, c0b2, c0ba, c0bb,
        c1w1, c1w2, c1wa, c1wb, c1b1, c1b2, c1ba, c1bb,
        c2w1, c2w2, c2wa, c2wb, c2b1, c2b2, c2ba, c2bb, out);

    head_kernel<<<(BATCH * TSTEPS) / 256, 256, 0, stream>>>(
        gw1, gb1, gw2, gb2, aw1, ab1, aw2, ab2, uw1, ub1, uw2, ub2, out);
}

// Round 5
// 5844.830 us; speedup vs baseline: 1.5642x; 1.1032x over previous
//
#include <hip/hip_runtime.h>
#include <math.h>

#define BATCH 128
#define TSTEPS 4096
#define INDIM 13

// LDS layout (256 floats, fully zero-initialized each launch):
//  zL[0:96]  = smem+0    [x(13) | o0(35) | o1(23) | o2(6) | pad(19)] LSTM input
//  z0[0:64]  = smem+96   [x(13) | h0_lstm(35) | pad(16)]             CfC0 input
//  z1[0:64]  = smem+160  [o0(35) | h1_lstm(23) | pad(6)]             CfC1 input
//  z2[0:32]  = smem+224  [o1(23) | h2_lstm(6) | pad(3)]              CfC2 input

__device__ __forceinline__ float fsig(float x) {
    return __builtin_amdgcn_rcpf(1.f + __expf(-x));
}
__device__ __forceinline__ float ftanh(float x) {
    float s = fsig(x + x);
    return s + s - 1.f;
}
__device__ __forceinline__ float fsoftplus(float x) {
    return (x > 15.f) ? x : __logf(1.f + __expf(x));
}

// lane-quad exchanges via DPP (VALU latency, not LDS pipe)
__device__ __forceinline__ float qxor1(float v) {   // quad_perm [1,0,3,2]
    return __int_as_float(__builtin_amdgcn_update_dpp(
        0, __float_as_int(v), 0xB1, 0xF, 0xF, true));
}
__device__ __forceinline__ float qxor2(float v) {   // quad_perm [2,3,0,1]
    return __int_as_float(__builtin_amdgcn_update_dpp(
        0, __float_as_int(v), 0x4E, 0xF, 0xF, true));
}
__device__ __forceinline__ float sxor4(float v) {   // ds_swizzle xor-4
    return __int_as_float(__builtin_amdgcn_ds_swizzle(
        __float_as_int(v), 0x101F));
}
// 8-lane butterfly allreduce; identical op order on all lanes -> bit-identical
#define BFLY8(a) { a += sxor4(a); a += qxor2(a); a += qxor1(a); }

// acc += dot(float4 zv, 4 named weight scalars W_q_{0..3})
#define FMA4(acc, W, q, zv) { acc += zv.x * W##_##q##_0; acc += zv.y * W##_##q##_1; \
                              acc += zv.z * W##_##q##_2; acc += zv.w * W##_##q##_3; }

__global__ __launch_bounds__(512, 2)
void rnn_kernel(const float* __restrict__ x,
                const float* __restrict__ lstm_wi, const float* __restrict__ lstm_wh,
                const float* __restrict__ lstm_b,
                const float* __restrict__ c0w1, const float* __restrict__ c0w2,
                const float* __restrict__ c0wa, const float* __restrict__ c0wb,
                const float* __restrict__ c0b1, const float* __restrict__ c0b2,
                const float* __restrict__ c0ba, const float* __restrict__ c0bb,
                const float* __restrict__ c1w1, const float* __restrict__ c1w2,
                const float* __restrict__ c1wa, const float* __restrict__ c1wb,
                const float* __restrict__ c1b1, const float* __restrict__ c1b2,
                const float* __restrict__ c1ba, const float* __restrict__ c1bb,
                const float* __restrict__ c2w1, const float* __restrict__ c2w2,
                const float* __restrict__ c2wa, const float* __restrict__ c2wb,
                const float* __restrict__ c2b1, const float* __restrict__ c2b2,
                const float* __restrict__ c2ba, const float* __restrict__ c2bb,
                float* __restrict__ out)
{
    const int bb = blockIdx.x;
    const int t  = threadIdx.x;     // 0..511
    const int k  = t & 7;           // K-chunk slot within the octet
    const int u  = t >> 3;          // unit / row-group index 0..63

    __shared__ __align__(16) float smem[256];
    float* zL = smem;
    float* z0 = smem + 96;
    float* z1 = smem + 160;
    float* z2 = smem + 224;

    const long xbase = (long)bb * TSTEPS * INDIM;
    const long obase = (long)bb * TSTEPS * 6;

    // ---- LSTM weights: lane (u,k) holds cols [12k,12k+12) of all 4 gate rows
    auto lwf = [&](int A, int c) -> float {
        int r = A * 64 + u;
        return (c < 13) ? lstm_wi[r * 13 + c]
             : (c < 77) ? lstm_wh[r * 64 + (c - 13)] : 0.f;
    };
#define DEF_WL(A,q) \
    float wl##A##_##q##_0 = lwf(A, 12*k + 4*q + 0); \
    float wl##A##_##q##_1 = lwf(A, 12*k + 4*q + 1); \
    float wl##A##_##q##_2 = lwf(A, 12*k + 4*q + 2); \
    float wl##A##_##q##_3 = lwf(A, 12*k + 4*q + 3);
    DEF_WL(0,0) DEF_WL(0,1) DEF_WL(0,2)
    DEF_WL(1,0) DEF_WL(1,1) DEF_WL(1,2)
    DEF_WL(2,0) DEF_WL(2,1) DEF_WL(2,2)
    DEF_WL(3,0) DEF_WL(3,1) DEF_WL(3,2)
#undef DEF_WL
    const float bL0 = lstm_b[u];
    const float bL1 = lstm_b[64 + u];
    const float bL2 = lstm_b[128 + u];
    const float bL3 = lstm_b[192 + u];

    // ---- CfC weights: octet groups (disjoint lane sets, one name overlay)
    // grp0 (u<35):  row u,    len 48, chunk 8 at 8k
    // grp1 (u<58):  row u-35, len 58, chunk 8 at 8k
    // grp2 (u>=58): row u-58, len 29, chunk 4 at 4k
    const int grp  = (u < 35) ? 0 : (u < 58) ? 1 : 2;
    const int row  = (grp == 0) ? u : (grp == 1) ? (u - 35) : (u - 58);
    const int rl   = (grp == 0) ? 48 : (grp == 1) ? 58 : 29;
    const int clen = (grp == 2) ? 4 : 8;
    const int cb   = (grp == 2) ? 4 * k : 8 * k;
    const float *W0p, *W1p, *W2p, *W3p;
    float bC0, bC1, bC2, bC3;
    if (grp == 0) {
        W0p = c0w1 + row * 48; W1p = c0w2 + row * 48;
        W2p = c0wa + row * 48; W3p = c0wb + row * 48;
        bC0 = c0b1[row]; bC1 = c0b2[row]; bC2 = c0ba[row]; bC3 = c0bb[row];
    } else if (grp == 1) {
        W0p = c1w1 + row * 58; W1p = c1w2 + row * 58;
        W2p = c1wa + row * 58; W3p = c1wb + row * 58;
        bC0 = c1b1[row]; bC1 = c1b2[row]; bC2 = c1ba[row]; bC3 = c1bb[row];
    } else {
        W0p = c2w1 + row * 29; W1p = c2w2 + row * 29;
        W2p = c2wa + row * 29; W3p = c2wb + row * 29;
        bC0 = c2b1[row]; bC1 = c2b2[row]; bC2 = c2ba[row]; bC3 = c2bb[row];
    }
    auto cwf = [&](const float* W, int c) -> float {
        int cc = cb + c;
        return (c < clen && cc < rl) ? W[cc] : 0.f;
    };
#define DEF_WC(A,q) \
    float wc##A##_##q##_0 = cwf(W##A##p, 4*q + 0); \
    float wc##A##_##q##_1 = cwf(W##A##p, 4*q + 1); \
    float wc##A##_##q##_2 = cwf(W##A##p, 4*q + 2); \
    float wc##A##_##q##_3 = cwf(W##A##p, 4*q + 3);
    DEF_WC(0,0) DEF_WC(0,1)
    DEF_WC(1,0) DEF_WC(1,1)
    DEF_WC(2,0) DEF_WC(2,1)
    DEF_WC(3,0) DEF_WC(3,1)
#undef DEF_WC

    const bool pfl = (t >= 128 && t < 141);  // x-prefetch lanes (grp0, idle ph4)
    float creg = 0.f;                         // cell state, replicated per octet

    // ---- init LDS: zero everything, then x_0 ----
    if (t < 256) smem[t] = 0.f;
    __syncthreads();
    if (t < 13) zL[t] = x[xbase + t];
    __syncthreads();

    #pragma unroll 1
    for (int ts = 0; ts < TSTEPS; ++ts) {
        // ---- phase 1: LSTM (all 512 lanes; K-split by k) ----
        float xn = 0.f;
        if (pfl && (ts + 1) < TSTEPS)
            xn = x[xbase + (long)(ts + 1) * 13 + (t - 128)];
        if (t >= 256 && t < 269) z0[t - 256] = zL[t - 256];  // x_t -> CfC0 input
        {
            const float4* zc = (const float4*)(zL + 12 * k);
            float4 q0 = zc[0], q1 = zc[1], q2 = zc[2];
            float a0 = 0.f, a1 = 0.f, a2 = 0.f, a3 = 0.f;
            FMA4(a0, wl0, 0, q0) FMA4(a0, wl0, 1, q1) FMA4(a0, wl0, 2, q2)
            FMA4(a1, wl1, 0, q0) FMA4(a1, wl1, 1, q1) FMA4(a1, wl1, 2, q2)
            FMA4(a2, wl2, 0, q0) FMA4(a2, wl2, 1, q1) FMA4(a2, wl2, 2, q2)
            FMA4(a3, wl3, 0, q0) FMA4(a3, wl3, 1, q1) FMA4(a3, wl3, 2, q2)
            BFLY8(a0) BFLY8(a1) BFLY8(a2) BFLY8(a3)
            a0 += bL0; a1 += bL1; a2 += bL2; a3 += bL3;   // ia, ig, fg, og
            float cn = creg * fsig(a2 + 1.f) + ftanh(a0) * fsig(a1);
            creg = cn;                      // bit-identical on all 8 octet lanes
            float hl = ftanh(cn) * fsig(a3);
            if (k == 0) {
                if (u < 35)      z0[13 + u] = hl;   // h0
                else if (u < 58) z1[u]      = hl;   // h1 at z1[35..57]
                else             z2[u - 35] = hl;   // h2 at z2[23..28]
            }
        }
        __syncthreads();

        // ---- phase 2: CfC layer 0 (grp0; chunk 8 over z0) ----
        if (grp == 0) {
            const float4* zc = (const float4*)(z0 + 8 * k);
            float4 p0 = zc[0], p1 = zc[1];
            float a0 = 0.f, a1 = 0.f, a2 = 0.f, a3 = 0.f;
            FMA4(a0, wc0, 0, p0) FMA4(a0, wc0, 1, p1)
            FMA4(a1, wc1, 0, p0) FMA4(a1, wc1, 1, p1)
            FMA4(a2, wc2, 0, p0) FMA4(a2, wc2, 1, p1)
            FMA4(a3, wc3, 0, p0) FMA4(a3, wc3, 1, p1)
            BFLY8(a0) BFLY8(a1) BFLY8(a2) BFLY8(a3)
            a0 += bC0; a1 += bC1; a2 += bC2; a3 += bC3;
            float tg = fsig(a2 + a3);
            float f1 = ftanh(a0), f2 = ftanh(a1);
            float o = f1 + tg * (f2 - f1);
            if (k == 0) { z1[row] = o; zL[13 + row] = o; }
        }
        __syncthreads();

        // ---- phase 3: CfC layer 1 (grp1; chunk 8 over z1) ----
        if (grp == 1) {
            const float4* zc = (const float4*)(z1 + 8 * k);
            float4 p0 = zc[0], p1 = zc[1];
            float a0 = 0.f, a1 = 0.f, a2 = 0.f, a3 = 0.f;
            FMA4(a0, wc0, 0, p0) FMA4(a0, wc0, 1, p1)
            FMA4(a1, wc1, 0, p0) FMA4(a1, wc1, 1, p1)
            FMA4(a2, wc2, 0, p0) FMA4(a2, wc2, 1, p1)
            FMA4(a3, wc3, 0, p0) FMA4(a3, wc3, 1, p1)
            BFLY8(a0) BFLY8(a1) BFLY8(a2) BFLY8(a3)
            a0 += bC0; a1 += bC1; a2 += bC2; a3 += bC3;
            float tg = fsig(a2 + a3);
            float f1 = ftanh(a0), f2 = ftanh(a1);
            float o = f1 + tg * (f2 - f1);
            if (k == 0) { z2[row] = o; zL[48 + row] = o; }
        }
        __syncthreads();

        // ---- phase 4: CfC layer 2 (grp2; chunk 4 over z2) + x commit ----
        if (grp == 2) {
            const float4* zc = (const float4*)(z2 + 4 * k);
            float4 p0 = zc[0];
            float a0 = 0.f, a1 = 0.f, a2 = 0.f, a3 = 0.f;
            FMA4(a0, wc0, 0, p0)
            FMA4(a1, wc1, 0, p0)
            FMA4(a2, wc2, 0, p0)
            FMA4(a3, wc3, 0, p0)
            BFLY8(a0) BFLY8(a1) BFLY8(a2) BFLY8(a3)
            a0 += bC0; a1 += bC1; a2 += bC2; a3 += bC3;
            float tg = fsig(a2 + a3);
            float f1 = ftanh(a0), f2 = ftanh(a1);
            float o = f1 + tg * (f2 - f1);
            if (k == 0) {
                out[obase + (long)ts * 6 + row] = o;  // raw cfc_out
                zL[71 + row] = o;                     // new h[58:64]
            }
        } else if (pfl) {
            zL[t - 128] = xn;                         // commit x_{t+1}
        }
        __syncthreads();
    }
}

// ---- head: rewrite pred in place, write unc ----
#define S_GW1 0
#define S_GB1 192
#define S_GW2 224
#define S_GB2 320
#define S_AW1 323
#define S_AB1 515
#define S_AW2 547
#define S_AB2 643
#define S_UW1 646
#define S_UB1 742
#define S_UW2 758
#define S_UB2 854
#define S_TOT 860

__global__ __launch_bounds__(256)
void head_kernel(const float* __restrict__ gw1, const float* __restrict__ gb1,
                 const float* __restrict__ gw2, const float* __restrict__ gb2,
                 const float* __restrict__ aw1, const float* __restrict__ ab1,
                 const float* __restrict__ aw2, const float* __restrict__ ab2,
                 const float* __restrict__ uw1, const float* __restrict__ ub1,
                 const float* __restrict__ uw2, const float* __restrict__ ub2,
                 float* __restrict__ out)
{
    __shared__ float s[S_TOT];
    const int t = threadIdx.x;
    if (t < 192) { s[S_GW1 + t] = gw1[t]; s[S_AW1 + t] = aw1[t]; }
    if (t < 96)  { s[S_GW2 + t] = gw2[t]; s[S_AW2 + t] = aw2[t];
                   s[S_UW1 + t] = uw1[t]; s[S_UW2 + t] = uw2[t]; }
    if (t < 32)  { s[S_GB1 + t] = gb1[t]; s[S_AB1 + t] = ab1[t]; }
    if (t < 16)  { s[S_UB1 + t] = ub1[t]; }
    if (t < 3)   { s[S_GB2 + t] = gb2[t]; s[S_AB2 + t] = ab2[t]; }
    if (t < 6)   { s[S_UB2 + t] = ub2[t]; }
    __syncthreads();

    const long p = (long)blockIdx.x * 256 + t;   // < B*T exactly
    const long base = p * 6;
    float m0 = out[base+0], m1 = out[base+1], m2 = out[base+2];
    float m3 = out[base+3], m4 = out[base+4], m5 = out[base+5];

    float gy0 = s[S_GB2+0], gy1 = s[S_GB2+1], gy2 = s[S_GB2+2];
    float ac0 = s[S_AB2+0], ac1 = s[S_AB2+1], ac2 = s[S_AB2+2];
    #pragma unroll
    for (int i = 0; i < 32; ++i) {
        float hg = s[S_GB1+i] + s[S_GW1+i*6+0]*m0 + s[S_GW1+i*6+1]*m1
                 + s[S_GW1+i*6+2]*m2 + s[S_GW1+i*6+3]*m3
                 + s[S_GW1+i*6+4]*m4 + s[S_GW1+i*6+5]*m5;
        hg = ftanh(hg);
        gy0 += s[S_GW2+i]*hg; gy1 += s[S_GW2+32+i]*hg; gy2 += s[S_GW2+64+i]*hg;
        float ha = s[S_AB1+i] + s[S_AW1+i*6+0]*m0 + s[S_AW1+i*6+1]*m1
                 + s[S_AW1+i*6+2]*m2 + s[S_AW1+i*6+3]*m3
                 + s[S_AW1+i*6+4]*m4 + s[S_AW1+i*6+5]*m5;
        ha = ftanh(ha);
        ac0 += s[S_AW2+i]*ha; ac1 += s[S_AW2+32+i]*ha; ac2 += s[S_AW2+64+i]*ha;
    }
    float u0 = s[S_UB2+0], u1 = s[S_UB2+1], u2 = s[S_UB2+2];
    float u3 = s[S_UB2+3], u4 = s[S_UB2+4], u5 = s[S_UB2+5];
    #pragma unroll
    for (int i = 0; i < 16; ++i) {
        float hu = s[S_UB1+i] + s[S_UW1+i*6+0]*m0 + s[S_UW1+i*6+1]*m1
                 + s[S_UW1+i*6+2]*m2 + s[S_UW1+i*6+3]*m3
                 + s[S_UW1+i*6+4]*m4 + s[S_UW1+i*6+5]*m5;
        hu = fmaxf(hu, 0.f);
        u0 += s[S_UW2+i]*hu;      u1 += s[S_UW2+16+i]*hu; u2 += s[S_UW2+32+i]*hu;
        u3 += s[S_UW2+48+i]*hu;   u4 += s[S_UW2+64+i]*hu; u5 += s[S_UW2+80+i]*hu;
    }
    out[base+0] = gy0; out[base+1] = gy1; out[base+2] = gy2;
    out[base+3] = ac0; out[base+4] = ac1; out[base+5] = ac2;
    const long uoff = (long)BATCH * TSTEPS * 6;
    out[uoff+base+0] = fsoftplus(u0); out[uoff+base+1] = fsoftplus(u1);
    out[uoff+base+2] = fsoftplus(u2); out[uoff+base+3] = fsoftplus(u3);
    out[uoff+base+4] = fsoftplus(u4); out[uoff+base+5] = fsoftplus(u5);
}

extern "C" void kernel_launch(void* const* d_in, const int* in_sizes, int n_in,
                              void* d_out, int out_size, void* d_ws, size_t ws_size,
                              hipStream_t stream) {
    const float* x       = (const float*)d_in[0];
    const float* lstm_wi = (const float*)d_in[1];
    const float* lstm_wh = (const float*)d_in[2];
    const float* lstm_b  = (const float*)d_in[3];
    const float* c0w1 = (const float*)d_in[4];
    const float* c0w2 = (const float*)d_in[5];
    const float* c0wa = (const float*)d_in[6];
    const float* c0wb = (const float*)d_in[7];
    const float* c0b1 = (const float*)d_in[8];
    const float* c0b2 = (const float*)d_in[9];
    const float* c0ba = (const float*)d_in[10];
    const float* c0bb = (const float*)d_in[11];
    const float* c1w1 = (const float*)d_in[12];
    const float* c1w2 = (const float*)d_in[13];
    const float* c1wa = (const float*)d_in[14];
    const float* c1wb = (const float*)d_in[15];
    const float* c1b1 = (const float*)d_in[16];
    const float* c1b2 = (const float*)d_in[17];
    const float* c1ba = (const float*)d_in[18];
    const float* c1bb = (const float*)d_in[19];
    const float* c2w1 = (const float*)d_in[20];
    const float* c2w2 = (const float*)d_in[21];
    const float* c2wa = (const float*)d_in[22];
    const float* c2wb = (const float*)d_in[23];
    const float* c2b1 = (const float*)d_in[24];
    const float* c2b2 = (const float*)d_in[25];
    const float* c2ba = (const float*)d_in[26];
    const float* c2bb = (const float*)d_in[27];
    const float* gw1 = (const float*)d_in[28];
    const float* gb1 = (const float*)d_in[29];
    const float* gw2 = (const float*)d_in[30];
    const float* gb2 = (const float*)d_in[31];
    const float* aw1 = (const float*)d_in[32];
    const float* ab1 = (const float*)d_in[33];
    const float* aw2 = (const float*)d_in[34];
    const float* ab2 = (const float*)d_in[35];
    const float* uw1 = (const float*)d_in[36];
    const float* ub1 = (const float*)d_in[37];
    const float* uw2 = (const float*)d_in[38];
    const float* ub2 = (const float*)d_in[39];
    float* out = (float*)d_out;

    rnn_kernel<<<BATCH, 512, 0, stream>>>(x, lstm_wi, lstm_wh, lstm_b,
        c0w1, c0w2, c0wa, c0wb, c0b1, c0b2, c0ba, c0bb,
        c1w1, c1w2, c1wa, c1wb, c1b1, c1b2, c1ba, c1bb,
        c2w1, c2w2, c2wa, c2wb, c2b1, c2b2, c2ba, c2bb, out);

    head_kernel<<<(BATCH * TSTEPS) / 256, 256, 0, stream>>>(
        gw1, gb1, gw2, gb2, aw1, ab1, aw2, ab2, uw1, ub1, uw2, ub2, out);
}